// Round 1
// baseline (130.008 us; speedup 1.0000x reference)
//
#include <hip/hip_runtime.h>

#define N 256
#define D 1024
#define E 300
#define KCAP 5

// log2(e) and tau=0.1: sigmoid(d/tau) = 1/(1+exp(-10 d)) = 1/(1+exp2(-14.4269504 d))
#define NEG10_LOG2E (-14.4269504088896340f)
#define CLIP50_LOG2E (72.1347520444481700f)   // 50 * log2(e)

__device__ __forceinline__ float wave_sum(float v) {
#pragma unroll
    for (int o = 32; o >= 1; o >>= 1) v += __shfl_xor(v, o, 64);
    return v;
}

// ---------------- scores = v @ t^T (f32, vector ALU), also writes scores^T --------
__global__ __launch_bounds__(256) void scores_kernel(const float* __restrict__ v,
                                                     const float* __restrict__ t,
                                                     float* __restrict__ scores,
                                                     float* __restrict__ scoresT) {
    __shared__ float As[32][33];
    __shared__ float Bs[32][33];
    const int tid = threadIdx.x;
    const int tx = tid & 31, ty = tid >> 5;
    const int br = (blockIdx.x >> 3) * 32;
    const int bc = (blockIdx.x & 7) * 32;
    const int lr = tid >> 3;         // 0..31
    const int lc = (tid & 7) * 4;    // 0..28

    float acc[4] = {0.f, 0.f, 0.f, 0.f};

    for (int k0 = 0; k0 < D; k0 += 32) {
        float4 a = *(const float4*)(v + (size_t)(br + lr) * D + k0 + lc);
        float4 b = *(const float4*)(t + (size_t)(bc + lr) * D + k0 + lc);
        As[lr][lc + 0] = a.x; As[lr][lc + 1] = a.y; As[lr][lc + 2] = a.z; As[lr][lc + 3] = a.w;
        Bs[lr][lc + 0] = b.x; Bs[lr][lc + 1] = b.y; Bs[lr][lc + 2] = b.z; Bs[lr][lc + 3] = b.w;
        __syncthreads();
#pragma unroll
        for (int kk = 0; kk < 32; ++kk) {
            float bv = Bs[tx][kk];
#pragma unroll
            for (int q = 0; q < 4; ++q)
                acc[q] = fmaf(As[ty * 4 + q][kk], bv, acc[q]);
        }
        __syncthreads();
    }
#pragma unroll
    for (int q = 0; q < 4; ++q) {
        int gr = br + ty * 4 + q;
        int gc = bc + tx;
        scores[gr * N + gc] = acc[q];
        scoresT[gc * N + gr] = acc[q];
    }
}

// ---------------- relevance[n,m] = (1 + max_k cos(vte[n,k], tte[m])) / 2 ----------
__global__ __launch_bounds__(256) void relevance_kernel(const float* __restrict__ vte,
                                                        const float* __restrict__ tte,
                                                        float* __restrict__ rel) {
    __shared__ float inv_vn[KCAP];
    const int n = blockIdx.x;
    const int m = threadIdx.x;
    const float* base = vte + (size_t)n * KCAP * E;

    // inverse norms of the 5 v_text_emb rows for this n: 5 groups of 32 lanes
    if (threadIdx.x < 160) {
        int k = threadIdx.x >> 5;
        int l32 = threadIdx.x & 31;
        float s = 0.f;
        for (int e = l32; e < E; e += 32) {
            float x = base[k * E + e];
            s = fmaf(x, x, s);
        }
#pragma unroll
        for (int o = 16; o >= 1; o >>= 1) s += __shfl_xor(s, o, 32);
        if (l32 == 0) inv_vn[k] = 1.0f / sqrtf(s);
    }
    __syncthreads();

    const float* trow = tte + (size_t)m * E;
    float dot[KCAP] = {0.f, 0.f, 0.f, 0.f, 0.f};
    float sq = 0.f;
    for (int e4 = 0; e4 < E; e4 += 4) {
        float4 tv = *(const float4*)(trow + e4);
        sq = fmaf(tv.x, tv.x, fmaf(tv.y, tv.y, fmaf(tv.z, tv.z, fmaf(tv.w, tv.w, sq))));
#pragma unroll
        for (int k = 0; k < KCAP; ++k) {
            float4 vv = *(const float4*)(base + k * E + e4);
            dot[k] = fmaf(vv.x, tv.x, fmaf(vv.y, tv.y, fmaf(vv.z, tv.z, fmaf(vv.w, tv.w, dot[k]))));
        }
    }
    float inv_tn = 1.0f / sqrtf(sq);
    float best = dot[0] * inv_vn[0];
#pragma unroll
    for (int k = 1; k < KCAP; ++k) best = fmaxf(best, dot[k] * inv_vn[k]);
    best *= inv_tn;
    float r = 0.5f + 0.5f * best;
    rel[n * N + m] = (m == n) ? 1.0f : r;
}

// ---------------- unified rank kernel: mode 0 = idcg (rel), 1 = t (scores), 2 = v (scores^T)
__global__ __launch_bounds__(256) void rank_kernel(const float* __restrict__ scores,
                                                   const float* __restrict__ scoresT,
                                                   const float* __restrict__ rel,
                                                   float* __restrict__ idcg,
                                                   float* __restrict__ dcg_t,
                                                   float* __restrict__ rdcg_t,
                                                   float* __restrict__ dcg_v,
                                                   float* __restrict__ rdcg_v) {
    __shared__ float red[8];
    const int mode = blockIdx.x >> 8;   // 0,1,2
    const int i = blockIdx.x & 255;
    const int j = threadIdx.x;

    const float* srow = (mode == 0) ? (rel + i * N)
                       : (mode == 1) ? (scores + i * N)
                                     : (scoresT + i * N);
    const float sj = srow[j];
    const float gain = __builtin_amdgcn_exp2f(rel[i * N + j]) - 1.0f;

    float dcg_c = 0.f;
    int cnt = 0;
    if (mode == 0) {
#pragma unroll 8
        for (int k = 0; k < N; ++k) cnt += (srow[k] > sj) ? 1 : 0;
    } else {
        float soft = 0.f;
#pragma unroll 8
        for (int k = 0; k < N; ++k) {
            float d = srow[k] - sj;
            cnt += (d > 0.f) ? 1 : 0;
            float e2 = fminf(fmaxf(NEG10_LOG2E * d, -CLIP50_LOG2E), CLIP50_LOG2E);
            soft += __builtin_amdgcn_rcpf(1.0f + __builtin_amdgcn_exp2f(e2));
        }
        // loop included k==j which contributes exactly 0.5; soft_rk = (soft-0.5)+1
        float soft_rk = soft + 0.5f;
        dcg_c = gain * __builtin_amdgcn_rcpf(__builtin_amdgcn_logf(1.0f + soft_rk));
    }
    float real_rk = (float)(cnt + 1);
    float rdcg_c = gain * __builtin_amdgcn_rcpf(__builtin_amdgcn_logf(1.0f + real_rk));

    float a = wave_sum(dcg_c);
    float b = wave_sum(rdcg_c);
    const int w = j >> 6;
    if ((j & 63) == 0) { red[w] = a; red[w + 4] = b; }
    __syncthreads();
    if (j == 0) {
        float sa = red[0] + red[1] + red[2] + red[3];
        float sb = red[4] + red[5] + red[6] + red[7];
        if (mode == 0) idcg[i] = sb;
        else if (mode == 1) { dcg_t[i] = sa; rdcg_t[i] = sb; }
        else               { dcg_v[i] = sa; rdcg_v[i] = sb; }
    }
}

// ---------------- final scalars -------------------------------------------------
__global__ __launch_bounds__(256) void final_kernel(const float* __restrict__ idcg,
                                                    const float* __restrict__ dcg_t,
                                                    const float* __restrict__ rdcg_t,
                                                    const float* __restrict__ dcg_v,
                                                    const float* __restrict__ rdcg_v,
                                                    float* __restrict__ out) {
    __shared__ float red[16];
    const int i = threadIdx.x;
    float inv = 1.0f / idcg[i];
    float nt = dcg_t[i] * inv;
    float rnt = rdcg_t[i] * inv;
    float nv = dcg_v[i] * inv;
    float rnv = rdcg_v[i] * inv;
    nt = wave_sum(nt); rnt = wave_sum(rnt); nv = wave_sum(nv); rnv = wave_sum(rnv);
    const int w = i >> 6;
    if ((i & 63) == 0) { red[w] = nt; red[4 + w] = rnt; red[8 + w] = nv; red[12 + w] = rnv; }
    __syncthreads();
    if (i == 0) {
        float s_nt = red[0] + red[1] + red[2] + red[3];
        float s_rnt = red[4] + red[5] + red[6] + red[7];
        float s_nv = red[8] + red[9] + red[10] + red[11];
        float s_rnv = red[12] + red[13] + red[14] + red[15];
        const float c = 1.0f / 256.0f;
        float m_nt = s_nt * c, m_rnt = s_rnt * c, m_nv = s_nv * c, m_rnv = s_rnv * c;
        out[0] = ((1.0f - m_nt) + (1.0f - m_nv)) * 0.5f;
        out[1] = m_nt;
        out[2] = m_rnt;
        out[3] = m_nv;
        out[4] = m_rnv;
    }
}

extern "C" void kernel_launch(void* const* d_in, const int* in_sizes, int n_in,
                              void* d_out, int out_size, void* d_ws, size_t ws_size,
                              hipStream_t stream) {
    const float* v   = (const float*)d_in[0];
    const float* t   = (const float*)d_in[1];
    const float* vte = (const float*)d_in[2];
    const float* tte = (const float*)d_in[3];
    float* out = (float*)d_out;

    float* ws      = (float*)d_ws;
    float* scores  = ws;                 // 65536
    float* scoresT = ws + 65536;         // 65536
    float* rel     = ws + 131072;        // 65536
    float* idcg    = ws + 196608;        // 256
    float* dcg_t   = ws + 196864;        // 256
    float* rdcg_t  = ws + 197120;        // 256
    float* dcg_v   = ws + 197376;        // 256
    float* rdcg_v  = ws + 197632;        // 256

    scores_kernel<<<64, 256, 0, stream>>>(v, t, scores, scoresT);
    relevance_kernel<<<N, 256, 0, stream>>>(vte, tte, rel);
    rank_kernel<<<3 * N, 256, 0, stream>>>(scores, scoresT, rel,
                                           idcg, dcg_t, rdcg_t, dcg_v, rdcg_v);
    final_kernel<<<1, 256, 0, stream>>>(idcg, dcg_t, rdcg_t, dcg_v, rdcg_v, out);
}

// Round 4
// 94.894 us; speedup vs baseline: 1.3700x; 1.3700x over previous
//
#include <hip/hip_runtime.h>

#define N 256
#define D 1024
#define E 300
#define KCAP 5
#define KSPLIT 16

// tau=0.1: sigmoid(d/tau) = 1/(1+exp(-10 d)) = 1/(1+exp2(-14.4269504 d))
#define NEG10_LOG2E (-14.4269504088896340f)
#define CLIP50_LOG2E (72.1347520444481700f)   // 50 * log2(e)

__device__ __forceinline__ float wave_sum(float v) {
#pragma unroll
    for (int o = 32; o >= 1; o >>= 1) v += __shfl_xor(v, o, 64);
    return v;
}

// ---------------- fused: blocks 0..255 scores partials, 256..511 relevance -------
// scores: 64x64 tile x 64-K-chunk per block; part[kc][i][j] reduced later.
// relevance[n,m] = (1 + max_k cos(vte[n,k], tte[m])) / 2, diag forced to 1.
__global__ __launch_bounds__(256) void fused_part_rel_kernel(const float* __restrict__ v,
                                                             const float* __restrict__ t,
                                                             const float* __restrict__ vte,
                                                             const float* __restrict__ tte,
                                                             float* __restrict__ part,
                                                             float* __restrict__ rel) {
    __shared__ float AsT[64][64];   // [k][m] K-major so inner reads are b128
    __shared__ float BsT[64][64];   // [k][n]
    __shared__ float inv_vn[KCAP];
    const int tid = threadIdx.x;

    if (blockIdx.x < 256) {
        // ---------------- scores partial GEMM ----------------
        const int bid = blockIdx.x;
        const int kc   = bid & 15;           // K chunk
        const int tile = bid >> 4;           // 0..15
        const int tr = (tile >> 2) * 64;
        const int tc = (tile & 3) * 64;
        const int kb = kc * 64;

        const int m  = tid & 63;
        const int k0 = (tid >> 6) * 4;       // 0,4,8,12

#pragma unroll
        for (int pass = 0; pass < 4; ++pass) {
            int kk = k0 + pass * 16;
            float4 a = *(const float4*)(v + (size_t)(tr + m) * D + kb + kk);
            float4 b = *(const float4*)(t + (size_t)(tc + m) * D + kb + kk);
            AsT[kk + 0][m] = a.x; AsT[kk + 1][m] = a.y; AsT[kk + 2][m] = a.z; AsT[kk + 3][m] = a.w;
            BsT[kk + 0][m] = b.x; BsT[kk + 1][m] = b.y; BsT[kk + 2][m] = b.z; BsT[kk + 3][m] = b.w;
        }
        __syncthreads();

        const int tx = tid & 15;
        const int ty = tid >> 4;
        float acc[4][4] = {};
#pragma unroll 8
        for (int kk = 0; kk < 64; ++kk) {
            float4 a = *(const float4*)(&AsT[kk][ty * 4]);
            float4 b = *(const float4*)(&BsT[kk][tx * 4]);
            float av[4] = {a.x, a.y, a.z, a.w};
            float bv[4] = {b.x, b.y, b.z, b.w};
#pragma unroll
            for (int q = 0; q < 4; ++q)
#pragma unroll
                for (int p = 0; p < 4; ++p)
                    acc[q][p] = fmaf(av[q], bv[p], acc[q][p]);
        }

        float* pbase = part + (size_t)kc * (N * N);
#pragma unroll
        for (int q = 0; q < 4; ++q)
            *(float4*)(pbase + (size_t)(tr + ty * 4 + q) * N + tc + tx * 4) = *(float4*)acc[q];
    } else {
        // ---------------- relevance ----------------
        const int n = blockIdx.x - 256;
        const int m = tid;
        const float* base = vte + (size_t)n * KCAP * E;

        if (tid < 160) {
            int k = tid >> 5;
            int l32 = tid & 31;
            float s = 0.f;
            for (int e = l32; e < E; e += 32) {
                float x = base[k * E + e];
                s = fmaf(x, x, s);
            }
#pragma unroll
            for (int o = 16; o >= 1; o >>= 1) s += __shfl_xor(s, o, 32);
            if (l32 == 0) inv_vn[k] = 1.0f / sqrtf(s);
        }
        __syncthreads();

        const float* trow = tte + (size_t)m * E;
        float dot[KCAP] = {0.f, 0.f, 0.f, 0.f, 0.f};
        float sq = 0.f;
        for (int e4 = 0; e4 < E; e4 += 4) {
            float4 tv = *(const float4*)(trow + e4);
            sq = fmaf(tv.x, tv.x, fmaf(tv.y, tv.y, fmaf(tv.z, tv.z, fmaf(tv.w, tv.w, sq))));
#pragma unroll
            for (int k = 0; k < KCAP; ++k) {
                float4 vv = *(const float4*)(base + k * E + e4);
                dot[k] = fmaf(vv.x, tv.x, fmaf(vv.y, tv.y, fmaf(vv.z, tv.z, fmaf(vv.w, tv.w, dot[k]))));
            }
        }
        float inv_tn = 1.0f / sqrtf(sq);
        float best = dot[0] * inv_vn[0];
#pragma unroll
        for (int k = 1; k < KCAP; ++k) best = fmaxf(best, dot[k] * inv_vn[k]);
        best *= inv_tn;
        float r = 0.5f + 0.5f * best;
        rel[n * N + m] = (m == n) ? 1.0f : r;
    }
}

// ---------------- deterministic K-split reduce, also emits scores^T -------------
__global__ __launch_bounds__(256) void scores_reduce_kernel(const float* __restrict__ part,
                                                            float* __restrict__ scores,
                                                            float* __restrict__ scoresT) {
    const int i = blockIdx.x;
    const int j = threadIdx.x;
    float s = 0.f;
#pragma unroll
    for (int c = 0; c < KSPLIT; ++c) s += part[(size_t)c * (N * N) + i * N + j];
    scores[i * N + j] = s;
    scoresT[j * N + i] = s;
}

// ---------------- fallback scores (round-1) for small ws -----------------------
__global__ __launch_bounds__(256) void scores_kernel(const float* __restrict__ v,
                                                     const float* __restrict__ t,
                                                     float* __restrict__ scores,
                                                     float* __restrict__ scoresT) {
    __shared__ float As[32][33];
    __shared__ float Bs[32][33];
    const int tid = threadIdx.x;
    const int tx = tid & 31, ty = tid >> 5;
    const int br = (blockIdx.x >> 3) * 32;
    const int bc = (blockIdx.x & 7) * 32;
    const int lr = tid >> 3;
    const int lc = (tid & 7) * 4;

    float acc[4] = {0.f, 0.f, 0.f, 0.f};
    for (int k0 = 0; k0 < D; k0 += 32) {
        float4 a = *(const float4*)(v + (size_t)(br + lr) * D + k0 + lc);
        float4 b = *(const float4*)(t + (size_t)(bc + lr) * D + k0 + lc);
        As[lr][lc + 0] = a.x; As[lr][lc + 1] = a.y; As[lr][lc + 2] = a.z; As[lr][lc + 3] = a.w;
        Bs[lr][lc + 0] = b.x; Bs[lr][lc + 1] = b.y; Bs[lr][lc + 2] = b.z; Bs[lr][lc + 3] = b.w;
        __syncthreads();
#pragma unroll
        for (int kk = 0; kk < 32; ++kk) {
            float bv = Bs[tx][kk];
#pragma unroll
            for (int q = 0; q < 4; ++q)
                acc[q] = fmaf(As[ty * 4 + q][kk], bv, acc[q]);
        }
        __syncthreads();
    }
#pragma unroll
    for (int q = 0; q < 4; ++q) {
        int gr = br + ty * 4 + q;
        int gc = bc + tx;
        scores[gr * N + gc] = acc[q];
        scoresT[gc * N + gr] = acc[q];
    }
}

// ---------------- standalone relevance (fallback path) --------------------------
__global__ __launch_bounds__(256) void relevance_kernel(const float* __restrict__ vte,
                                                        const float* __restrict__ tte,
                                                        float* __restrict__ rel) {
    __shared__ float inv_vn[KCAP];
    const int n = blockIdx.x;
    const int m = threadIdx.x;
    const float* base = vte + (size_t)n * KCAP * E;

    if (threadIdx.x < 160) {
        int k = threadIdx.x >> 5;
        int l32 = threadIdx.x & 31;
        float s = 0.f;
        for (int e = l32; e < E; e += 32) {
            float x = base[k * E + e];
            s = fmaf(x, x, s);
        }
#pragma unroll
        for (int o = 16; o >= 1; o >>= 1) s += __shfl_xor(s, o, 32);
        if (l32 == 0) inv_vn[k] = 1.0f / sqrtf(s);
    }
    __syncthreads();

    const float* trow = tte + (size_t)m * E;
    float dot[KCAP] = {0.f, 0.f, 0.f, 0.f, 0.f};
    float sq = 0.f;
    for (int e4 = 0; e4 < E; e4 += 4) {
        float4 tv = *(const float4*)(trow + e4);
        sq = fmaf(tv.x, tv.x, fmaf(tv.y, tv.y, fmaf(tv.z, tv.z, fmaf(tv.w, tv.w, sq))));
#pragma unroll
        for (int k = 0; k < KCAP; ++k) {
            float4 vv = *(const float4*)(base + k * E + e4);
            dot[k] = fmaf(vv.x, tv.x, fmaf(vv.y, tv.y, fmaf(vv.z, tv.z, fmaf(vv.w, tv.w, dot[k]))));
        }
    }
    float inv_tn = 1.0f / sqrtf(sq);
    float best = dot[0] * inv_vn[0];
#pragma unroll
    for (int k = 1; k < KCAP; ++k) best = fmaxf(best, dot[k] * inv_vn[k]);
    best *= inv_tn;
    float r = 0.5f + 0.5f * best;
    rel[n * N + m] = (m == n) ? 1.0f : r;
}

// ---------------- unified rank kernel: mode 0 = idcg (rel), 1 = t, 2 = v ---------
__global__ __launch_bounds__(256) void rank_kernel(const float* __restrict__ scores,
                                                   const float* __restrict__ scoresT,
                                                   const float* __restrict__ rel,
                                                   float* __restrict__ idcg,
                                                   float* __restrict__ dcg_t,
                                                   float* __restrict__ rdcg_t,
                                                   float* __restrict__ dcg_v,
                                                   float* __restrict__ rdcg_v) {
    __shared__ float red[8];
    __shared__ float srow_s[N];
    const int mode = blockIdx.x >> 8;
    const int i = blockIdx.x & 255;
    const int j = threadIdx.x;

    const float* srow = (mode == 0) ? (rel + i * N)
                       : (mode == 1) ? (scores + i * N)
                                     : (scoresT + i * N);
    const float sj = srow[j];
    srow_s[j] = sj;                    // stage row: inner loop reads LDS broadcast
    const float gain = __builtin_amdgcn_exp2f(rel[i * N + j]) - 1.0f;
    __syncthreads();

    float dcg_c = 0.f;
    int cnt = 0;
    if (mode == 0) {
#pragma unroll 8
        for (int k = 0; k < N; ++k) cnt += (srow_s[k] > sj) ? 1 : 0;
    } else {
        float soft = 0.f;
#pragma unroll 8
        for (int k = 0; k < N; ++k) {
            float d = srow_s[k] - sj;
            cnt += (d > 0.f) ? 1 : 0;
            float e2 = fminf(fmaxf(NEG10_LOG2E * d, -CLIP50_LOG2E), CLIP50_LOG2E);
            soft += __builtin_amdgcn_rcpf(1.0f + __builtin_amdgcn_exp2f(e2));
        }
        float soft_rk = soft + 0.5f;   // k==j contributed exactly 0.5
        dcg_c = gain * __builtin_amdgcn_rcpf(__builtin_amdgcn_logf(1.0f + soft_rk));
    }
    float real_rk = (float)(cnt + 1);
    float rdcg_c = gain * __builtin_amdgcn_rcpf(__builtin_amdgcn_logf(1.0f + real_rk));

    float a = wave_sum(dcg_c);
    float b = wave_sum(rdcg_c);
    const int w = j >> 6;
    if ((j & 63) == 0) { red[w] = a; red[w + 4] = b; }
    __syncthreads();
    if (j == 0) {
        float sa = red[0] + red[1] + red[2] + red[3];
        float sb = red[4] + red[5] + red[6] + red[7];
        if (mode == 0) idcg[i] = sb;
        else if (mode == 1) { dcg_t[i] = sa; rdcg_t[i] = sb; }
        else               { dcg_v[i] = sa; rdcg_v[i] = sb; }
    }
}

// ---------------- final scalars -------------------------------------------------
__global__ __launch_bounds__(256) void final_kernel(const float* __restrict__ idcg,
                                                    const float* __restrict__ dcg_t,
                                                    const float* __restrict__ rdcg_t,
                                                    const float* __restrict__ dcg_v,
                                                    const float* __restrict__ rdcg_v,
                                                    float* __restrict__ out) {
    __shared__ float red[16];
    const int i = threadIdx.x;
    float inv = 1.0f / idcg[i];
    float nt = dcg_t[i] * inv;
    float rnt = rdcg_t[i] * inv;
    float nv = dcg_v[i] * inv;
    float rnv = rdcg_v[i] * inv;
    nt = wave_sum(nt); rnt = wave_sum(rnt); nv = wave_sum(nv); rnv = wave_sum(rnv);
    const int w = i >> 6;
    if ((i & 63) == 0) { red[w] = nt; red[4 + w] = rnt; red[8 + w] = nv; red[12 + w] = rnv; }
    __syncthreads();
    if (i == 0) {
        float s_nt = red[0] + red[1] + red[2] + red[3];
        float s_rnt = red[4] + red[5] + red[6] + red[7];
        float s_nv = red[8] + red[9] + red[10] + red[11];
        float s_rnv = red[12] + red[13] + red[14] + red[15];
        const float c = 1.0f / 256.0f;
        float m_nt = s_nt * c, m_rnt = s_rnt * c, m_nv = s_nv * c, m_rnv = s_rnv * c;
        out[0] = ((1.0f - m_nt) + (1.0f - m_nv)) * 0.5f;
        out[1] = m_nt;
        out[2] = m_rnt;
        out[3] = m_nv;
        out[4] = m_rnv;
    }
}

extern "C" void kernel_launch(void* const* d_in, const int* in_sizes, int n_in,
                              void* d_out, int out_size, void* d_ws, size_t ws_size,
                              hipStream_t stream) {
    const float* v   = (const float*)d_in[0];
    const float* t   = (const float*)d_in[1];
    const float* vte = (const float*)d_in[2];
    const float* tte = (const float*)d_in[3];
    float* out = (float*)d_out;
    float* ws  = (float*)d_ws;

    const size_t need = (size_t)(KSPLIT * N * N + 3 * N * N + 5 * N) * 4;

    float *scores, *scoresT, *rel, *idcg, *dcg_t, *rdcg_t, *dcg_v, *rdcg_v;
    if (ws_size >= need) {
        float* part = ws;                       // 16*65536
        scores  = ws + KSPLIT * N * N;
        scoresT = scores + N * N;
        rel     = scoresT + N * N;
        idcg    = rel + N * N;
        dcg_t   = idcg + N;
        rdcg_t  = dcg_t + N;
        dcg_v   = rdcg_t + N;
        rdcg_v  = dcg_v + N;
        fused_part_rel_kernel<<<512, 256, 0, stream>>>(v, t, vte, tte, part, rel);
        scores_reduce_kernel<<<N, 256, 0, stream>>>(part, scores, scoresT);
    } else {
        scores  = ws;
        scoresT = ws + N * N;
        rel     = ws + 2 * N * N;
        idcg    = ws + 3 * N * N;
        dcg_t   = idcg + N;
        rdcg_t  = dcg_t + N;
        dcg_v   = rdcg_t + N;
        rdcg_v  = dcg_v + N;
        scores_kernel<<<64, 256, 0, stream>>>(v, t, scores, scoresT);
        relevance_kernel<<<N, 256, 0, stream>>>(vte, tte, rel);
    }

    rank_kernel<<<3 * N, 256, 0, stream>>>(scores, scoresT, rel,
                                           idcg, dcg_t, rdcg_t, dcg_v, rdcg_v);
    final_kernel<<<1, 256, 0, stream>>>(idcg, dcg_t, rdcg_t, dcg_v, rdcg_v, out);
}